// Round 21
// baseline (496.827 us; speedup 1.0000x reference)
//
#include <hip/hip_runtime.h>
#include <hip/hip_bf16.h>

// ---------------------------------------------------------------------------
// MODEL (R0-R20): d_out = f32 buffer, layout
// [X_out N*Dout][ref_a E][backref E][e_map E][v_count 1]. Inputs f32/int32
// (runtime detectors adapt if bf16/int64).
// R21 = R19 (297.8us, nt reverted) + two-pass bucket scatter + fusions.
//   Scatter's 69-75MB writeback for 6.4MB payload = same-line writes spread
//   over whole kernel. Pass1 appends (dst,src) pairs bucket-append-only
//   (clean writeback); pass2 places within ~4KB hot windows per bucket.
//   Fused: hist into copy_idx; Xb+Xq conversion reads X once.
// ---------------------------------------------------------------------------

#define SCAN_BE 1024
#define BSH 6                      // 64 nodes per bucket

typedef __attribute__((ext_vector_type(8))) short bf16x8;
typedef __attribute__((ext_vector_type(4))) float f32x4;

__device__ __forceinline__ float bf2f(unsigned short u) {
    return __uint_as_float(((unsigned int)u) << 16);
}

__device__ __forceinline__ unsigned short f2bf(float f) {
    unsigned int b = __float_as_uint(f);
    unsigned int r = (b + 0x7FFFu + ((b >> 16) & 1u)) >> 16;
    return (unsigned short)r;
}

// f32 -> OCP e4m3fn (RNE, saturate to 448) — R17-proven.
__device__ __forceinline__ unsigned char f2e4m3(float f) {
    unsigned int u = __float_as_uint(f);
    unsigned char s = (unsigned char)((u >> 24) & 0x80u);
    unsigned int ua = u & 0x7FFFFFFFu;
    float a = __uint_as_float(ua);
    if (!(a < 448.0f)) return (unsigned char)(s | 0x7E);
    if (a < 0x1p-10f) return s;
    int E = (int)(ua >> 23);
    int e = E - 120;
    unsigned int M = ua & 0x7FFFFFu;
    if (e >= 1) {
        unsigned int r = M + 0x7FFFFu + ((M >> 20) & 1u);
        unsigned int m = r >> 20;
        if (m >= 8) { m = 0; e++; }
        if (e >= 16 || (e == 15 && m == 7))
            return (unsigned char)(s | 0x7E);
        return (unsigned char)(s | (e << 3) | (m & 7));
    } else {
        int m = (int)(a * 512.0f + 0.5f);
        if (m >= 8) return (unsigned char)(s | 0x08);
        return (unsigned char)(s | m);
    }
}

__device__ __forceinline__ float4 load4f(const void* p, size_t off, int isbf) {
    if (isbf) {
        ushort4 u = *(const ushort4*)((const unsigned short*)p + off);
        return make_float4(bf2f(u.x), bf2f(u.y), bf2f(u.z), bf2f(u.w));
    }
    return *(const float4*)((const float*)p + off);
}

// flags[0]=1 if float inputs bf16-packed; flags[1]=1 if indices int64.
__global__ void detect_kernel(const unsigned int* __restrict__ Xw,
                              const unsigned int* __restrict__ bw,
                              int* __restrict__ flags) {
    __shared__ int c_bf16, c_i64;
    int t = threadIdx.x;
    if (t == 0) { c_bf16 = 0; c_i64 = 0; }
    __syncthreads();
    int local = 0;
    #pragma unroll
    for (int k = 0; k < 4; k++) {
        unsigned int w = Xw[t * 4 + k];
        unsigned int e = (w >> 7) & 0xFFu;
        if (e >= 96u && e <= 143u) local++;
    }
    atomicAdd(&c_bf16, local);
    atomicAdd(&c_i64, (bw[2 * t + 1] == 0u) ? 1 : 0);
    __syncthreads();
    if (t == 0) {
        flags[0] = (c_bf16 >= 512) ? 1 : 0;
        flags[1] = (c_i64 == 256) ? 1 : 0;
    }
}

__global__ void zero_kernel(float4* __restrict__ p, long long n4) {
    long long i = (long long)blockIdx.x * blockDim.x + threadIdx.x;
    long long stride = (long long)gridDim.x * blockDim.x;
    for (; i < n4; i += stride)
        p[i] = make_float4(0.f, 0.f, 0.f, 0.f);
}

__global__ void zero_i32(int* __restrict__ p, long long n) {
    long long i = (long long)blockIdx.x * blockDim.x + threadIdx.x;
    long long stride = (long long)gridDim.x * blockDim.x;
    for (; i < n; i += stride) p[i] = 0;
}

__global__ void fill_zero_f32(float* __restrict__ p, long long lo, long long hi) {
    long long i = lo + (long long)blockIdx.x * blockDim.x + threadIdx.x;
    long long stride = (long long)gridDim.x * blockDim.x;
    for (; i < hi; i += stride) p[i] = 0.f;
}

// Fused X conversion: one read of X, writes Xb (bf16) and optionally Xq (fp8).
__global__ void xconv_dual_kernel(const void* __restrict__ Xraw,
                                  const int* __restrict__ flags,
                                  unsigned short* __restrict__ Xb,
                                  unsigned char* __restrict__ Xq,
                                  int writeq, long long n4) {
    long long i = (long long)blockIdx.x * blockDim.x + threadIdx.x;
    long long stride = (long long)gridDim.x * blockDim.x;
    const int isbf = flags[0];
    for (; i < n4; i += stride) {
        float4 v = load4f(Xraw, (size_t)i * 4, isbf);
        ushort4 u;
        u.x = f2bf(v.x); u.y = f2bf(v.y);
        u.z = f2bf(v.z); u.w = f2bf(v.w);
        *(ushort4*)(Xb + i * 4) = u;
        if (writeq) {
            uchar4 q;
            q.x = f2e4m3(v.x); q.y = f2e4m3(v.y);
            q.z = f2e4m3(v.z); q.w = f2e4m3(v.w);
            *(uchar4*)(Xq + i * 4) = q;
        }
    }
}

// W,Wp -> FRAGMENT-PACKED bf16 Wf (R16); bias -> f32.
__global__ void wtrans_frag_kernel(const void* __restrict__ W,
                                   const void* __restrict__ Wp,
                                   const void* __restrict__ bias,
                                   const int* __restrict__ flags,
                                   unsigned short* __restrict__ Wtf,
                                   unsigned short* __restrict__ Wptf,
                                   float* __restrict__ biasf, int D) {
    const int isbf = flags[0];
    int i = blockIdx.x * blockDim.x + threadIdx.x;
    if (i < 2048) {
        int lane = i & 63;
        int ctkc = i >> 6;
        int kc = ctkc & 3;
        int ct = ctkc >> 2;
        int lr = lane & 15, lg = lane >> 4;
        int n = ct * 16 + lr;
        #pragma unroll
        for (int e = 0; e < 8; e++) {
            int k = kc * 32 + 16 * (e >> 2) + 4 * lg + (e & 3);
            size_t src = (size_t)k * D + n;
            float w  = isbf ? bf2f(((const unsigned short*)W)[src])
                            : ((const float*)W)[src];
            float wp = isbf ? bf2f(((const unsigned short*)Wp)[src])
                            : ((const float*)Wp)[src];
            Wtf [(size_t)i * 8 + e] = f2bf(w);
            Wptf[(size_t)i * 8 + e] = f2bf(wp);
        }
    }
    if (i < D) {
        biasf[i] = isbf ? bf2f(((const unsigned short*)bias)[i])
                        : ((const float*)bias)[i];
    }
}

// Fused: index outputs as f32 + dst histogram (counts += 1 per edge).
__global__ void copy_idx_hist_kernel(const int* __restrict__ ref_a,
                                     const int* __restrict__ backref,
                                     const int* __restrict__ e_map,
                                     const int* __restrict__ v_count,
                                     const int* __restrict__ flags,
                                     float* __restrict__ out,
                                     int* __restrict__ counts,
                                     long long base, long long E) {
    long long i = (long long)blockIdx.x * blockDim.x + threadIdx.x;
    const int is64 = flags[1];
    if (i < E) {
        out[base + i] = (float)ref_a[is64 ? 2 * i : i];
        atomicAdd(&counts[backref[is64 ? 2 * i : i]], 1);
    } else if (i < 2 * E) {
        long long k = i - E;
        out[base + i] = (float)backref[is64 ? 2 * k : k];
    } else if (i < 3 * E) {
        out[base + i] = (float)e_map[i - 2 * E];
    } else if (i == 3 * E) {
        out[base + i] = (float)v_count[0];
    }
}

// ---------------- scan (3-phase, R13-proven) ----------------
__global__ __launch_bounds__(256) void block_reduce_kernel(
    const int* __restrict__ counts, int* __restrict__ bsum, int n) {
    __shared__ int sd[256];
    int b = blockIdx.x, t = threadIdx.x;
    int lo = b * SCAN_BE;
    int hi = lo + SCAN_BE; if (hi > n) hi = n;
    int s = 0;
    for (int i = lo + t; i < hi; i += 256) s += counts[i];
    sd[t] = s;
    __syncthreads();
    for (int d = 128; d > 0; d >>= 1) {
        if (t < d) sd[t] += sd[t + d];
        __syncthreads();
    }
    if (t == 0) bsum[b] = sd[0];
}

__global__ __launch_bounds__(1024) void scan_bsum_kernel(
    int* __restrict__ bsum, int nb, int* __restrict__ offsets, int n) {
    __shared__ int sd[1024];
    int t = threadIdx.x;
    int v = (t < nb) ? bsum[t] : 0;
    sd[t] = v;
    __syncthreads();
    for (int d = 1; d < 1024; d <<= 1) {
        int x = (t >= d) ? sd[t - d] : 0;
        __syncthreads();
        sd[t] += x;
        __syncthreads();
    }
    if (t < nb) bsum[t] = (t == 0) ? 0 : sd[t - 1];
    if (t == 1023) offsets[n] = sd[1023];
}

__global__ __launch_bounds__(256) void block_scan_kernel(
    const int* counts, const int* __restrict__ bsum,
    int* __restrict__ offsets, int* cursor, int n) {
    __shared__ int ts[256];
    int b = blockIdx.x, t = threadIdx.x;
    int base0 = b * SCAN_BE + t * 4;
    int c0 = (base0 + 0 < n) ? counts[base0 + 0] : 0;
    int c1 = (base0 + 1 < n) ? counts[base0 + 1] : 0;
    int c2 = (base0 + 2 < n) ? counts[base0 + 2] : 0;
    int c3 = (base0 + 3 < n) ? counts[base0 + 3] : 0;
    ts[t] = c0 + c1 + c2 + c3;
    __syncthreads();
    for (int d = 1; d < 256; d <<= 1) {
        int x = (t >= d) ? ts[t - d] : 0;
        __syncthreads();
        ts[t] += x;
        __syncthreads();
    }
    int ex = bsum[b] + (t ? ts[t - 1] : 0);
    if (base0 + 0 < n) { offsets[base0 + 0] = ex; cursor[base0 + 0] = ex; } ex += c0;
    if (base0 + 1 < n) { offsets[base0 + 1] = ex; cursor[base0 + 1] = ex; } ex += c1;
    if (base0 + 2 < n) { offsets[base0 + 2] = ex; cursor[base0 + 2] = ex; } ex += c2;
    if (base0 + 3 < n) { offsets[base0 + 3] = ex; cursor[base0 + 3] = ex; }
}

__global__ __launch_bounds__(1024) void scan_kernel(
    const int* counts, int* __restrict__ offsets, int* cursor, int n) {
    __shared__ int part[1024];
    int t = threadIdx.x;
    int chunk = (n + 1023) / 1024;
    int lo = t * chunk;
    int hi = lo + chunk; if (hi > n) hi = n;
    int s = 0;
    for (int i = lo; i < hi; i++) s += counts[i];
    part[t] = s;
    __syncthreads();
    for (int d = 1; d < 1024; d <<= 1) {
        int v = (t >= d) ? part[t - d] : 0;
        __syncthreads();
        part[t] += v;
        __syncthreads();
    }
    int run = (t == 0) ? 0 : part[t - 1];
    for (int i = lo; i < hi; i++) {
        int c = counts[i];
        offsets[i] = run;
        cursor[i]  = run;
        run += c;
    }
    if (t == 1023) offsets[n] = part[1023];
}

// ---------------- two-pass bucket scatter ----------------
// bucket b covers nodes [b<<BSH, (b+1)<<BSH); its pair region is the same
// slice of the CSR layout: [offsets[n0], offsets[n1]).
__global__ void binit_kernel(const int* __restrict__ offsets,
                             int* __restrict__ bcur, int nbk, int N) {
    int b = blockIdx.x * blockDim.x + threadIdx.x;
    if (b < nbk) {
        int node = b << BSH;
        if (node > N) node = N;
        bcur[b] = offsets[node];
    }
}

// Pass 1: append (dst,src) pairs into bucket regions (clean writeback).
__global__ void bucket_pass1_kernel(const int* __restrict__ src,
                                    const int* __restrict__ dst,
                                    const int* __restrict__ flags,
                                    int* __restrict__ bcur,
                                    long long* __restrict__ pairs,
                                    long long E) {
    long long i = (long long)blockIdx.x * blockDim.x + threadIdx.x;
    long long stride = (long long)gridDim.x * blockDim.x;
    const int is64 = flags[1];
    for (; i < E; i += stride) {
        long long ei = is64 ? 2 * i : i;
        int d = dst[ei];
        int s = src[ei];
        int pos = atomicAdd(&bcur[d >> BSH], 1);
        pairs[pos] = ((long long)d << 32) | (unsigned int)s;
    }
}

// Pass 2: per bucket, place pairs at final cursor positions (hot 4KB window).
__global__ __launch_bounds__(256) void bucket_pass2_kernel(
    const long long* __restrict__ pairs, const int* __restrict__ offsets,
    int* __restrict__ cursor, int* __restrict__ srcs, int N) {
    int b = blockIdx.x;
    int n0 = b << BSH;
    int n1 = n0 + (1 << BSH); if (n1 > N) n1 = N;
    if (n0 >= N) return;
    int lo = offsets[n0], hi = offsets[n1];
    for (int i = lo + threadIdx.x; i < hi; i += blockDim.x) {
        long long p = pairs[i];
        int d = (int)(p >> 32);
        int s = (int)(p & 0xFFFFFFFFll);
        int pos = atomicAdd(&cursor[d], 1);
        srcs[pos] = s;
    }
}

// Fallback: XCD-range-partitioned scatter (R19, plain loads).
__global__ void scatter_xcd_kernel(const int* __restrict__ src,
                                   const int* __restrict__ dst,
                                   const int* __restrict__ flags,
                                   int* __restrict__ cursor,
                                   int* __restrict__ srcs,
                                   long long E, int N, int nstripes) {
    int b = blockIdx.x;
    int r = b & 7;
    int s = b >> 3;
    int rchunk = (N + 7) / 8;
    int rlo = r * rchunk;
    int rhi = rlo + rchunk; if (rhi > N) rhi = N;
    long long e0 = (long long)s * E / nstripes;
    long long e1 = (long long)(s + 1) * E / nstripes;
    const int is64 = flags[1];
    for (long long i = e0 + threadIdx.x; i < e1; i += blockDim.x) {
        long long ei = is64 ? 2 * i : i;
        int d = dst[ei];
        if (d < rlo || d >= rhi) continue;
        int sv = src[ei];
        int pos = atomicAdd(&cursor[d], 1);
        srcs[pos] = sv;
    }
}

// Branchless e4m3 decode-accumulate (R19-proven).
__device__ __forceinline__ void acc_fp8x4(float4& acc, unsigned int q) {
    unsigned int b0 = ((q << 24) & 0x80000000u) | ((q << 20) & 0x07F00000u);
    unsigned int b1 = ((q << 16) & 0x80000000u) | ((q << 12) & 0x07F00000u);
    unsigned int b2 = ((q <<  8) & 0x80000000u) | ((q <<  4) & 0x07F00000u);
    unsigned int b3 = ( q        & 0x80000000u) | ((q >>  4) & 0x07F00000u);
    acc.x = fmaf(__uint_as_float(b0), 0x1p120f, acc.x);
    acc.y = fmaf(__uint_as_float(b1), 0x1p120f, acc.y);
    acc.z = fmaf(__uint_as_float(b2), 0x1p120f, acc.z);
    acc.w = fmaf(__uint_as_float(b3), 0x1p120f, acc.w);
}

// Gather aggregation fp8 -> bf16 Ab, branchless decode, 2-way unroll.
__global__ void csr_agg_f8b_kernel(const unsigned char* __restrict__ Xq,
                                   const int* __restrict__ offsets,
                                   const int* __restrict__ srcs,
                                   unsigned short* __restrict__ Ab,
                                   int N, int D) {
    int g = (int)(((long long)blockIdx.x * blockDim.x + threadIdx.x) >> 5);
    int lane = threadIdx.x & 31;
    if (g >= N) return;
    int lo = offsets[g], hi = offsets[g + 1];
    for (int c = lane * 4; c < D; c += 128) {
        float4 acc = make_float4(0.f, 0.f, 0.f, 0.f);
        int i = lo;
        for (; i + 1 < hi; i += 2) {
            int s0 = srcs[i], s1 = srcs[i + 1];
            unsigned int q0 = *(const unsigned int*)(Xq + (size_t)s0 * D + c);
            unsigned int q1 = *(const unsigned int*)(Xq + (size_t)s1 * D + c);
            acc_fp8x4(acc, q0);
            acc_fp8x4(acc, q1);
        }
        if (i < hi) {
            int s0 = srcs[i];
            unsigned int q0 = *(const unsigned int*)(Xq + (size_t)s0 * D + c);
            acc_fp8x4(acc, q0);
        }
        ushort4 o;
        o.x = f2bf(acc.x); o.y = f2bf(acc.y);
        o.z = f2bf(acc.z); o.w = f2bf(acc.w);
        *(ushort4*)(Ab + (size_t)g * D + c) = o;
    }
}

// Gather aggregation bf16->bf16 (fallback).
__global__ void csr_agg_b2b_kernel(const unsigned short* __restrict__ Xb,
                                   const int* __restrict__ offsets,
                                   const int* __restrict__ srcs,
                                   unsigned short* __restrict__ Ab,
                                   int N, int D) {
    int g = (int)(((long long)blockIdx.x * blockDim.x + threadIdx.x) >> 5);
    int lane = threadIdx.x & 31;
    if (g >= N) return;
    int lo = offsets[g], hi = offsets[g + 1];
    for (int c = lane * 4; c < D; c += 128) {
        float4 acc = make_float4(0.f, 0.f, 0.f, 0.f);
        for (int i = lo; i < hi; i++) {
            int s = srcs[i];
            ushort4 u = *(const ushort4*)(Xb + (size_t)s * D + c);
            acc.x += bf2f(u.x); acc.y += bf2f(u.y);
            acc.z += bf2f(u.z); acc.w += bf2f(u.w);
        }
        ushort4 o;
        o.x = f2bf(acc.x); o.y = f2bf(acc.y);
        o.z = f2bf(acc.z); o.w = f2bf(acc.w);
        *(ushort4*)(Ab + (size_t)g * D + c) = o;
    }
}

// Gather aggregation from f32 X (fallback when Xb doesn't fit ws).
__global__ void csr_agg_kernel(const void* __restrict__ Xraw,
                               const int* __restrict__ offsets,
                               const int* __restrict__ srcs,
                               const int* __restrict__ flags,
                               float* __restrict__ A, int N, int D) {
    int g = (int)(((long long)blockIdx.x * blockDim.x + threadIdx.x) >> 5);
    int lane = threadIdx.x & 31;
    if (g >= N) return;
    const int isbf = flags[0];
    int lo = offsets[g], hi = offsets[g + 1];
    for (int c = lane * 4; c < D; c += 128) {
        float4 acc = make_float4(0.f, 0.f, 0.f, 0.f);
        for (int i = lo; i < hi; i++) {
            int s = srcs[i];
            float4 v = load4f(Xraw, (size_t)s * D + c, isbf);
            acc.x += v.x; acc.y += v.y; acc.z += v.z; acc.w += v.w;
        }
        *(float4*)(A + (size_t)g * D + c) = acc;
    }
}

// ---------------- MFMA GEMM (fragment-packed B) — R16 verbatim ----------------
__global__ __launch_bounds__(256) void gemm_mfma_kernel(
    const unsigned short* __restrict__ Xb,
    const unsigned short* __restrict__ Ab,
    const unsigned short* __restrict__ Wtf,
    const unsigned short* __restrict__ Wptf,
    const float* __restrict__ biasf,
    float* __restrict__ out, long long Nw) {
    const int D = 128;
    const int wave = threadIdx.x >> 6;
    const int lane = threadIdx.x & 63;
    const int lr = lane & 15;
    const int lg = lane >> 4;
    const long long rbase = ((long long)blockIdx.x * 4 + wave) * 16;
    if (rbase >= Nw) return;

    long long arow = rbase + lr;
    if (arow >= Nw) arow = Nw - 1;
    const unsigned short* xrow = Xb + arow * D;
    const unsigned short* prow = Ab + arow * D;

    f32x4 acc[8];
    #pragma unroll
    for (int i = 0; i < 8; i++) acc[i] = (f32x4){0.f, 0.f, 0.f, 0.f};

    for (int kc = 0; kc < 8; kc++) {
        const bool xpart = (kc < 4);
        const unsigned short* arow_p = xpart ? xrow : prow;
        const unsigned short* wf     = xpart ? Wtf : Wptf;
        const int kk = kc & 3;
        const int k0 = kk * 32 + 4 * lg;

        ushort4 alo = *(const ushort4*)(arow_p + k0);
        ushort4 ahi = *(const ushort4*)(arow_p + k0 + 16);
        bf16x8 a = {(short)alo.x, (short)alo.y, (short)alo.z, (short)alo.w,
                    (short)ahi.x, (short)ahi.y, (short)ahi.z, (short)ahi.w};

        #pragma unroll
        for (int ct = 0; ct < 8; ct++) {
            bf16x8 b = *(const bf16x8*)(wf +
                           ((size_t)((ct * 4 + kk) * 64 + lane)) * 8);
            acc[ct] = __builtin_amdgcn_mfma_f32_16x16x32_bf16(a, b, acc[ct],
                                                              0, 0, 0);
        }
    }

    #pragma unroll
    for (int ct = 0; ct < 8; ct++) {
        int n = ct * 16 + lr;
        float bn = biasf[n];
        #pragma unroll
        for (int r = 0; r < 4; r++) {
            long long m = rbase + 4 * lg + r;
            if (m < Nw) {
                float v = acc[ct][r] + bn;
                out[m * D + n] = v > 0.f ? v : 0.f;
            }
        }
    }
}

// ---------------- fallbacks (R9/R13-proven) ----------------
__global__ void edge_agg_kernel(const void* __restrict__ Xraw,
                                const int* __restrict__ src,
                                const int* __restrict__ dst,
                                const int* __restrict__ flags,
                                float* __restrict__ A,
                                long long E, int D, int row0, int row1) {
    long long tid = (long long)blockIdx.x * blockDim.x + threadIdx.x;
    long long e = tid >> 5;
    int lane = (int)(tid & 31);
    if (e >= E) return;
    const int is64 = flags[1];
    const int isbf = flags[0];
    long long ei = is64 ? 2 * e : e;
    int d = dst[ei];
    if (d < row0 || d >= row1) return;
    int s = src[ei];
    for (int c = lane * 4; c < D; c += 128) {
        float4 v = load4f(Xraw, (size_t)s * D + c, isbf);
        float* a = A + (size_t)(d - row0) * D + c;
        atomicAdd(a + 0, v.x);
        atomicAdd(a + 1, v.y);
        atomicAdd(a + 2, v.z);
        atomicAdd(a + 3, v.w);
    }
}

__global__ void copy_idx_kernel(const int* __restrict__ ref_a,
                                const int* __restrict__ backref,
                                const int* __restrict__ e_map,
                                const int* __restrict__ v_count,
                                const int* __restrict__ flags,
                                float* __restrict__ out,
                                long long base, long long E) {
    long long i = (long long)blockIdx.x * blockDim.x + threadIdx.x;
    const int is64 = flags[1];
    if (i < E) {
        out[base + i] = (float)ref_a[is64 ? 2 * i : i];
    } else if (i < 2 * E) {
        long long k = i - E;
        out[base + i] = (float)backref[is64 ? 2 * k : k];
    } else if (i < 3 * E) {
        out[base + i] = (float)e_map[i - 2 * E];
    } else if (i == 3 * E) {
        out[base + i] = (float)v_count[0];
    }
}

__global__ __launch_bounds__(256) void gemm_fused_kernel(
    const void* __restrict__ Xraw, const float* __restrict__ A,
    const void* __restrict__ Wraw, const void* __restrict__ Wpraw,
    const void* __restrict__ braw, const int* __restrict__ flags,
    float* __restrict__ out, long long row0, long long rend) {
    const int D = 128;
    __shared__ float sX[64][68];
    __shared__ float sW[64][68];

    const long long rbase = row0 + (long long)blockIdx.x * 64;
    const int cbase = blockIdx.y * 64;
    const int t  = threadIdx.x;
    const int tx = t & 15;
    const int ty = t >> 4;
    const int isbf = flags[0];

    float acc[4][4] = {};

    for (int kk = 0; kk < 256; kk += 64) {
        const bool first = (kk < 128);
        const void* Ws = first ? Wraw : Wpraw;
        const int kc = kk & 127;

        #pragma unroll
        for (int i = 0; i < 4; i++) {
            int r  = ty + i * 16;
            int c4 = tx * 4;
            long long grow = rbase + r;
            float4 v = make_float4(0.f, 0.f, 0.f, 0.f);
            if (grow < rend) {
                if (first)
                    v = load4f(Xraw, (size_t)grow * D + kc + c4, isbf);
                else
                    v = *(const float4*)(A + (size_t)(grow - row0) * D + kc + c4);
            }
            *(float4*)&sX[r][c4] = v;
            float4 w = load4f(Ws, (size_t)(kc + r) * D + cbase + c4, isbf);
            *(float4*)&sW[r][c4] = w;
        }
        __syncthreads();

        #pragma unroll
        for (int k4 = 0; k4 < 16; k4++) {
            float4 xv[4], wv[4];
            #pragma unroll
            for (int i = 0; i < 4; i++)
                xv[i] = *(float4*)&sX[ty * 4 + i][k4 * 4];
            #pragma unroll
            for (int i = 0; i < 4; i++)
                wv[i] = *(float4*)&sW[k4 * 4 + i][tx * 4];
            #pragma unroll
            for (int ki = 0; ki < 4; ki++) {
                #pragma unroll
                for (int r = 0; r < 4; r++) {
                    float x = (ki == 0) ? xv[r].x
                            : (ki == 1) ? xv[r].y
                            : (ki == 2) ? xv[r].z
                                        : xv[r].w;
                    acc[r][0] += x * wv[ki].x;
                    acc[r][1] += x * wv[ki].y;
                    acc[r][2] += x * wv[ki].z;
                    acc[r][3] += x * wv[ki].w;
                }
            }
        }
        __syncthreads();
    }

    const long long grow0 = rbase + ty * 4;
    const int gcol0 = cbase + tx * 4;
    float b0, b1, b2, b3;
    if (isbf) {
        const unsigned short* bb = (const unsigned short*)braw;
        b0 = bf2f(bb[gcol0 + 0]); b1 = bf2f(bb[gcol0 + 1]);
        b2 = bf2f(bb[gcol0 + 2]); b3 = bf2f(bb[gcol0 + 3]);
    } else {
        const float* bb = (const float*)braw;
        b0 = bb[gcol0 + 0]; b1 = bb[gcol0 + 1];
        b2 = bb[gcol0 + 2]; b3 = bb[gcol0 + 3];
    }
    #pragma unroll
    for (int r = 0; r < 4; r++) {
        long long grow = grow0 + r;
        if (grow >= rend) break;
        float4 v;
        v.x = acc[r][0] + b0; v.x = v.x > 0.f ? v.x : 0.f;
        v.y = acc[r][1] + b1; v.y = v.y > 0.f ? v.y : 0.f;
        v.z = acc[r][2] + b2; v.z = v.z > 0.f ? v.z : 0.f;
        v.w = acc[r][3] + b3; v.w = v.w > 0.f ? v.w : 0.f;
        *(float4*)(out + (size_t)grow * D + gcol0) = v;
    }
}

// ---------------------------------------------------------------------------
extern "C" void kernel_launch(void* const* d_in, const int* in_sizes, int n_in,
                              void* d_out, int out_size, void* d_ws, size_t ws_size,
                              hipStream_t stream) {
    const void* X       = d_in[0];
    const int*  ref_a   = (const int*)d_in[1];
    const int*  backref = (const int*)d_in[2];
    const int*  e_map   = (const int*)d_in[3];
    const int*  v_count = (const int*)d_in[4];
    const void* W       = d_in[5];
    const void* W_prop  = d_in[6];
    const void* bias    = d_in[7];
    float* out = (float*)d_out;

    int Dout = (n_in > 7 && in_sizes[7] > 0) ? in_sizes[7] : 128;
    int Din  = (in_sizes[5] > 0 && in_sizes[5] % Dout == 0)
                   ? in_sizes[5] / Dout : Dout;
    long long N = in_sizes[0] / Din;
    long long E = in_sizes[1];
    long long base = (long long)out_size - 3 * E - 1;
    if (base < 0) base = N * Dout;
    int nbk = (int)((N + (1 << BSH) - 1) >> BSH);

    // ---- workspace layout ----
    auto align256 = [](size_t x) { return (x + 255) & ~(size_t)255; };
    size_t o_flags = 0;
    size_t o_off   = align256(o_flags + 256);
    size_t o_cur   = align256(o_off + (size_t)(N + 1) * 4);
    size_t o_bsum  = align256(o_cur + (size_t)N * 4);
    size_t o_srcs  = align256(o_bsum + 1024 * 4);
    size_t o_A     = align256(o_srcs + (size_t)E * 4);
    size_t o_Xb    = align256(o_A + (size_t)N * Din * 4);
    size_t o_Wt    = align256(o_Xb + (size_t)N * Din * 2);
    size_t o_Wpt   = align256(o_Wt + (size_t)Din * Dout * 2);
    size_t o_bf    = align256(o_Wpt + (size_t)Din * Dout * 2);
    size_t o_Xq    = align256(o_bf + (size_t)Dout * 4);
    size_t o_bcur  = align256(o_Xq + (size_t)N * Din);
    size_t o_pairs = align256(o_bcur + (size_t)(nbk + 1) * 4);
    size_t need_csr  = o_Xb;
    size_t need_mfma = o_Xq;
    size_t need_fp8  = o_bcur;
    size_t need_bkt  = o_pairs + (size_t)E * 8;
    const bool use_csr  = (ws_size >= need_csr);
    const bool use_mfma = (ws_size >= need_mfma) && (Din == 128) && (Dout == 128);
    const bool use_fp8  = (ws_size >= need_fp8) && use_mfma;
    const bool use_bkt  = (ws_size >= need_bkt) && use_csr;

    char* wsb = (char*)d_ws;
    int*            flags   = (int*)(wsb + o_flags);
    int*            offsets = (int*)(wsb + o_off);
    int*            cursor  = (int*)(wsb + o_cur);
    int*            bsum    = (int*)(wsb + o_bsum);
    int*            srcs    = (int*)(wsb + o_srcs);
    float*          A       = use_csr ? (float*)(wsb + o_A) : (float*)(wsb + 256);
    unsigned short* Ab      = (unsigned short*)(wsb + o_A);
    unsigned short* Xb      = (unsigned short*)(wsb + o_Xb);
    unsigned short* Wtf     = (unsigned short*)(wsb + o_Wt);
    unsigned short* Wptf    = (unsigned short*)(wsb + o_Wpt);
    float*          biasf   = (float*)(wsb + o_bf);
    unsigned char*  Xq      = (unsigned char*)(wsb + o_Xq);
    int*            bcur    = (int*)(wsb + o_bcur);
    long long*      pairs   = (long long*)(wsb + o_pairs);

    detect_kernel<<<1, 256, 0, stream>>>((const unsigned int*)X,
                                         (const unsigned int*)backref, flags);

    long long Nw = N;
    long long cap = base / Dout;
    if (cap < Nw) Nw = cap;
    if (N * Dout < base)
        fill_zero_f32<<<2048, 1024, 0, stream>>>(out, N * Dout, base);

    if (use_csr) {
        // ---- counts=0; fused idx copy + histogram ----
        zero_i32<<<256, 256, 0, stream>>>(cursor, N);
        {
            long long total = 3 * E + 1;
            int blocks = (int)((total + 255) / 256);
            copy_idx_hist_kernel<<<blocks, 256, 0, stream>>>(
                ref_a, backref, e_map, v_count, flags, out, cursor, base, E);
        }
        // ---- 3-phase scan -> offsets, cursor ----
        int nb = (int)((N + SCAN_BE - 1) / SCAN_BE);
        if (nb <= 1024) {
            block_reduce_kernel<<<nb, 256, 0, stream>>>(cursor, bsum, (int)N);
            scan_bsum_kernel<<<1, 1024, 0, stream>>>(bsum, nb, offsets, (int)N);
            block_scan_kernel<<<nb, 256, 0, stream>>>(cursor, bsum, offsets,
                                                      cursor, (int)N);
        } else {
            scan_kernel<<<1, 1024, 0, stream>>>(cursor, offsets, cursor, (int)N);
        }
        // ---- scatter: two-pass bucket (or XCD fallback) ----
        if (use_bkt) {
            binit_kernel<<<(nbk + 255) / 256, 256, 0, stream>>>(offsets, bcur,
                                                                nbk, (int)N);
            bucket_pass1_kernel<<<2048, 256, 0, stream>>>(ref_a, backref, flags,
                                                          bcur, pairs, E);
            bucket_pass2_kernel<<<nbk, 256, 0, stream>>>(pairs, offsets,
                                                         cursor, srcs, (int)N);
        } else {
            const int nstripes = 256;
            scatter_xcd_kernel<<<8 * nstripes, 256, 0, stream>>>(
                ref_a, backref, flags, cursor, srcs, E, (int)N, nstripes);
        }

        if (use_mfma) {
            {
                long long n4 = (N * (long long)Din) / 4;
                int cblocks = (int)((n4 + 1023) / 1024);
                if (cblocks > 2048) cblocks = 2048;
                xconv_dual_kernel<<<cblocks, 1024, 0, stream>>>(
                    X, flags, Xb, Xq, use_fp8 ? 1 : 0, n4);
            }
            wtrans_frag_kernel<<<8, 256, 0, stream>>>(W, W_prop, bias, flags,
                                                      Wtf, Wptf, biasf, Din);
            {
                long long threads = N * 32;
                int blocks = (int)((threads + 255) / 256);
                if (use_fp8)
                    csr_agg_f8b_kernel<<<blocks, 256, 0, stream>>>(
                        Xq, offsets, srcs, Ab, (int)N, Din);
                else
                    csr_agg_b2b_kernel<<<blocks, 256, 0, stream>>>(
                        Xb, offsets, srcs, Ab, (int)N, Din);
            }
            {
                int blocks = (int)((Nw + 63) / 64);
                gemm_mfma_kernel<<<blocks, 256, 0, stream>>>(Xb, Ab, Wtf, Wptf,
                                                             biasf, out, Nw);
            }
        } else {
            {
                long long threads = N * 32;
                int blocks = (int)((threads + 255) / 256);
                csr_agg_kernel<<<blocks, 256, 0, stream>>>(X, offsets, srcs,
                                                           flags, A, (int)N, Din);
            }
            dim3 grid((unsigned)((Nw + 63) / 64), 2);
            gemm_fused_kernel<<<grid, 256, 0, stream>>>(X, A, W, W_prop, bias,
                                                        flags, out, 0, Nw);
        }
    } else {
        // ---- fallback: chunked atomic path (R9-proven) ----
        {
            long long total = 3 * E + 1;
            int blocks = (int)((total + 255) / 256);
            copy_idx_kernel<<<blocks, 256, 0, stream>>>(ref_a, backref, e_map,
                                                        v_count, flags, out,
                                                        base, E);
        }
        size_t avail = (ws_size > 256) ? ws_size - 256 : 0;
        size_t rows_cap = avail / ((size_t)Din * sizeof(float));
        long long rows_per;
        if (rows_cap >= (size_t)Nw) rows_per = Nw > 0 ? Nw : 1;
        else {
            rows_per = (long long)(rows_cap & ~(size_t)63);
            if (rows_per <= 0) rows_per = 64;
        }
        for (long long row0 = 0; row0 < Nw; row0 += rows_per) {
            long long rows = (Nw - row0 < rows_per) ? (Nw - row0) : rows_per;
            long long rend = row0 + rows;
            {   long long n4 = (rows * (long long)Din) / 4;
                int blocks = (int)((n4 + 1023) / 1024);
                if (blocks > 2048) blocks = 2048;
                if (blocks > 0)
                    zero_kernel<<<blocks, 1024, 0, stream>>>((float4*)A, n4);
            }
            {   long long threads = E * 32;
                int blocks = (int)((threads + 255) / 256);
                edge_agg_kernel<<<blocks, 256, 0, stream>>>(X, ref_a, backref,
                                                            flags, A, E, Din,
                                                            (int)row0, (int)rend);
            }
            {   dim3 grid((unsigned)((rows + 63) / 64), 2);
                gemm_fused_kernel<<<grid, 256, 0, stream>>>(X, A, W, W_prop,
                                                            bias, flags, out,
                                                            row0, rend);
            }
        }
    }
}

// Round 22
// 281.727 us; speedup vs baseline: 1.7635x; 1.7635x over previous
//
#include <hip/hip_runtime.h>
#include <hip/hip_bf16.h>

// ---------------------------------------------------------------------------
// MODEL (R0-R21): d_out = f32 buffer, layout
// [X_out N*Dout][ref_a E][backref E][e_map E][v_count 1]. Inputs f32/int32
// (runtime detectors adapt if bf16/int64).
// R22 = R19 structure (297.8us best) + R21's two safe fusions only.
//   R21's bucket scatter REVERTED: 1563 bucket cursors ping-ponged across
//   8 non-coherent L2s -> 239us pure stall. scatter_xcd (74us) restored.
//   Kept: copy_idx+hist fusion, single-read Xb/Xq dual conversion.
// ---------------------------------------------------------------------------

#define SCAN_BE 1024

typedef __attribute__((ext_vector_type(8))) short bf16x8;
typedef __attribute__((ext_vector_type(4))) float f32x4;

__device__ __forceinline__ float bf2f(unsigned short u) {
    return __uint_as_float(((unsigned int)u) << 16);
}

__device__ __forceinline__ unsigned short f2bf(float f) {
    unsigned int b = __float_as_uint(f);
    unsigned int r = (b + 0x7FFFu + ((b >> 16) & 1u)) >> 16;
    return (unsigned short)r;
}

// f32 -> OCP e4m3fn (RNE, saturate to 448) — R17-proven.
__device__ __forceinline__ unsigned char f2e4m3(float f) {
    unsigned int u = __float_as_uint(f);
    unsigned char s = (unsigned char)((u >> 24) & 0x80u);
    unsigned int ua = u & 0x7FFFFFFFu;
    float a = __uint_as_float(ua);
    if (!(a < 448.0f)) return (unsigned char)(s | 0x7E);
    if (a < 0x1p-10f) return s;
    int E = (int)(ua >> 23);
    int e = E - 120;
    unsigned int M = ua & 0x7FFFFFu;
    if (e >= 1) {
        unsigned int r = M + 0x7FFFFu + ((M >> 20) & 1u);
        unsigned int m = r >> 20;
        if (m >= 8) { m = 0; e++; }
        if (e >= 16 || (e == 15 && m == 7))
            return (unsigned char)(s | 0x7E);
        return (unsigned char)(s | (e << 3) | (m & 7));
    } else {
        int m = (int)(a * 512.0f + 0.5f);
        if (m >= 8) return (unsigned char)(s | 0x08);
        return (unsigned char)(s | m);
    }
}

__device__ __forceinline__ float4 load4f(const void* p, size_t off, int isbf) {
    if (isbf) {
        ushort4 u = *(const ushort4*)((const unsigned short*)p + off);
        return make_float4(bf2f(u.x), bf2f(u.y), bf2f(u.z), bf2f(u.w));
    }
    return *(const float4*)((const float*)p + off);
}

// flags[0]=1 if float inputs bf16-packed; flags[1]=1 if indices int64.
__global__ void detect_kernel(const unsigned int* __restrict__ Xw,
                              const unsigned int* __restrict__ bw,
                              int* __restrict__ flags) {
    __shared__ int c_bf16, c_i64;
    int t = threadIdx.x;
    if (t == 0) { c_bf16 = 0; c_i64 = 0; }
    __syncthreads();
    int local = 0;
    #pragma unroll
    for (int k = 0; k < 4; k++) {
        unsigned int w = Xw[t * 4 + k];
        unsigned int e = (w >> 7) & 0xFFu;
        if (e >= 96u && e <= 143u) local++;
    }
    atomicAdd(&c_bf16, local);
    atomicAdd(&c_i64, (bw[2 * t + 1] == 0u) ? 1 : 0);
    __syncthreads();
    if (t == 0) {
        flags[0] = (c_bf16 >= 512) ? 1 : 0;
        flags[1] = (c_i64 == 256) ? 1 : 0;
    }
}

__global__ void zero_kernel(float4* __restrict__ p, long long n4) {
    long long i = (long long)blockIdx.x * blockDim.x + threadIdx.x;
    long long stride = (long long)gridDim.x * blockDim.x;
    for (; i < n4; i += stride)
        p[i] = make_float4(0.f, 0.f, 0.f, 0.f);
}

__global__ void zero_i32(int* __restrict__ p, long long n) {
    long long i = (long long)blockIdx.x * blockDim.x + threadIdx.x;
    long long stride = (long long)gridDim.x * blockDim.x;
    for (; i < n; i += stride) p[i] = 0;
}

__global__ void fill_zero_f32(float* __restrict__ p, long long lo, long long hi) {
    long long i = lo + (long long)blockIdx.x * blockDim.x + threadIdx.x;
    long long stride = (long long)gridDim.x * blockDim.x;
    for (; i < hi; i += stride) p[i] = 0.f;
}

// Fused X conversion: one read of X, writes Xb (bf16) and optionally Xq (fp8).
__global__ void xconv_dual_kernel(const void* __restrict__ Xraw,
                                  const int* __restrict__ flags,
                                  unsigned short* __restrict__ Xb,
                                  unsigned char* __restrict__ Xq,
                                  int writeq, long long n4) {
    long long i = (long long)blockIdx.x * blockDim.x + threadIdx.x;
    long long stride = (long long)gridDim.x * blockDim.x;
    const int isbf = flags[0];
    for (; i < n4; i += stride) {
        float4 v = load4f(Xraw, (size_t)i * 4, isbf);
        ushort4 u;
        u.x = f2bf(v.x); u.y = f2bf(v.y);
        u.z = f2bf(v.z); u.w = f2bf(v.w);
        *(ushort4*)(Xb + i * 4) = u;
        if (writeq) {
            uchar4 q;
            q.x = f2e4m3(v.x); q.y = f2e4m3(v.y);
            q.z = f2e4m3(v.z); q.w = f2e4m3(v.w);
            *(uchar4*)(Xq + i * 4) = q;
        }
    }
}

// W,Wp -> FRAGMENT-PACKED bf16 Wf (R16); bias -> f32.
__global__ void wtrans_frag_kernel(const void* __restrict__ W,
                                   const void* __restrict__ Wp,
                                   const void* __restrict__ bias,
                                   const int* __restrict__ flags,
                                   unsigned short* __restrict__ Wtf,
                                   unsigned short* __restrict__ Wptf,
                                   float* __restrict__ biasf, int D) {
    const int isbf = flags[0];
    int i = blockIdx.x * blockDim.x + threadIdx.x;
    if (i < 2048) {
        int lane = i & 63;
        int ctkc = i >> 6;
        int kc = ctkc & 3;
        int ct = ctkc >> 2;
        int lr = lane & 15, lg = lane >> 4;
        int n = ct * 16 + lr;
        #pragma unroll
        for (int e = 0; e < 8; e++) {
            int k = kc * 32 + 16 * (e >> 2) + 4 * lg + (e & 3);
            size_t src = (size_t)k * D + n;
            float w  = isbf ? bf2f(((const unsigned short*)W)[src])
                            : ((const float*)W)[src];
            float wp = isbf ? bf2f(((const unsigned short*)Wp)[src])
                            : ((const float*)Wp)[src];
            Wtf [(size_t)i * 8 + e] = f2bf(w);
            Wptf[(size_t)i * 8 + e] = f2bf(wp);
        }
    }
    if (i < D) {
        biasf[i] = isbf ? bf2f(((const unsigned short*)bias)[i])
                        : ((const float*)bias)[i];
    }
}

// Fused: index outputs as f32 + dst histogram.
__global__ void copy_idx_hist_kernel(const int* __restrict__ ref_a,
                                     const int* __restrict__ backref,
                                     const int* __restrict__ e_map,
                                     const int* __restrict__ v_count,
                                     const int* __restrict__ flags,
                                     float* __restrict__ out,
                                     int* __restrict__ counts,
                                     long long base, long long E) {
    long long i = (long long)blockIdx.x * blockDim.x + threadIdx.x;
    const int is64 = flags[1];
    if (i < E) {
        out[base + i] = (float)ref_a[is64 ? 2 * i : i];
        atomicAdd(&counts[backref[is64 ? 2 * i : i]], 1);
    } else if (i < 2 * E) {
        long long k = i - E;
        out[base + i] = (float)backref[is64 ? 2 * k : k];
    } else if (i < 3 * E) {
        out[base + i] = (float)e_map[i - 2 * E];
    } else if (i == 3 * E) {
        out[base + i] = (float)v_count[0];
    }
}

// ---------------- scan (3-phase, R13-proven) ----------------
__global__ __launch_bounds__(256) void block_reduce_kernel(
    const int* __restrict__ counts, int* __restrict__ bsum, int n) {
    __shared__ int sd[256];
    int b = blockIdx.x, t = threadIdx.x;
    int lo = b * SCAN_BE;
    int hi = lo + SCAN_BE; if (hi > n) hi = n;
    int s = 0;
    for (int i = lo + t; i < hi; i += 256) s += counts[i];
    sd[t] = s;
    __syncthreads();
    for (int d = 128; d > 0; d >>= 1) {
        if (t < d) sd[t] += sd[t + d];
        __syncthreads();
    }
    if (t == 0) bsum[b] = sd[0];
}

__global__ __launch_bounds__(1024) void scan_bsum_kernel(
    int* __restrict__ bsum, int nb, int* __restrict__ offsets, int n) {
    __shared__ int sd[1024];
    int t = threadIdx.x;
    int v = (t < nb) ? bsum[t] : 0;
    sd[t] = v;
    __syncthreads();
    for (int d = 1; d < 1024; d <<= 1) {
        int x = (t >= d) ? sd[t - d] : 0;
        __syncthreads();
        sd[t] += x;
        __syncthreads();
    }
    if (t < nb) bsum[t] = (t == 0) ? 0 : sd[t - 1];
    if (t == 1023) offsets[n] = sd[1023];
}

__global__ __launch_bounds__(256) void block_scan_kernel(
    const int* counts, const int* __restrict__ bsum,
    int* __restrict__ offsets, int* cursor, int n) {
    __shared__ int ts[256];
    int b = blockIdx.x, t = threadIdx.x;
    int base0 = b * SCAN_BE + t * 4;
    int c0 = (base0 + 0 < n) ? counts[base0 + 0] : 0;
    int c1 = (base0 + 1 < n) ? counts[base0 + 1] : 0;
    int c2 = (base0 + 2 < n) ? counts[base0 + 2] : 0;
    int c3 = (base0 + 3 < n) ? counts[base0 + 3] : 0;
    ts[t] = c0 + c1 + c2 + c3;
    __syncthreads();
    for (int d = 1; d < 256; d <<= 1) {
        int x = (t >= d) ? ts[t - d] : 0;
        __syncthreads();
        ts[t] += x;
        __syncthreads();
    }
    int ex = bsum[b] + (t ? ts[t - 1] : 0);
    if (base0 + 0 < n) { offsets[base0 + 0] = ex; cursor[base0 + 0] = ex; } ex += c0;
    if (base0 + 1 < n) { offsets[base0 + 1] = ex; cursor[base0 + 1] = ex; } ex += c1;
    if (base0 + 2 < n) { offsets[base0 + 2] = ex; cursor[base0 + 2] = ex; } ex += c2;
    if (base0 + 3 < n) { offsets[base0 + 3] = ex; cursor[base0 + 3] = ex; }
}

__global__ __launch_bounds__(1024) void scan_kernel(
    const int* counts, int* __restrict__ offsets, int* cursor, int n) {
    __shared__ int part[1024];
    int t = threadIdx.x;
    int chunk = (n + 1023) / 1024;
    int lo = t * chunk;
    int hi = lo + chunk; if (hi > n) hi = n;
    int s = 0;
    for (int i = lo; i < hi; i++) s += counts[i];
    part[t] = s;
    __syncthreads();
    for (int d = 1; d < 1024; d <<= 1) {
        int v = (t >= d) ? part[t - d] : 0;
        __syncthreads();
        part[t] += v;
        __syncthreads();
    }
    int run = (t == 0) ? 0 : part[t - 1];
    for (int i = lo; i < hi; i++) {
        int c = counts[i];
        offsets[i] = run;
        cursor[i]  = run;
        run += c;
    }
    if (t == 1023) offsets[n] = part[1023];
}

// XCD-range-partitioned scatter (R19-proven, plain loads).
__global__ void scatter_xcd_kernel(const int* __restrict__ src,
                                   const int* __restrict__ dst,
                                   const int* __restrict__ flags,
                                   int* __restrict__ cursor,
                                   int* __restrict__ srcs,
                                   long long E, int N, int nstripes) {
    int b = blockIdx.x;
    int r = b & 7;
    int s = b >> 3;
    int rchunk = (N + 7) / 8;
    int rlo = r * rchunk;
    int rhi = rlo + rchunk; if (rhi > N) rhi = N;
    long long e0 = (long long)s * E / nstripes;
    long long e1 = (long long)(s + 1) * E / nstripes;
    const int is64 = flags[1];
    for (long long i = e0 + threadIdx.x; i < e1; i += blockDim.x) {
        long long ei = is64 ? 2 * i : i;
        int d = dst[ei];
        if (d < rlo || d >= rhi) continue;
        int sv = src[ei];
        int pos = atomicAdd(&cursor[d], 1);
        srcs[pos] = sv;
    }
}

// Branchless e4m3 decode-accumulate (R19-proven).
__device__ __forceinline__ void acc_fp8x4(float4& acc, unsigned int q) {
    unsigned int b0 = ((q << 24) & 0x80000000u) | ((q << 20) & 0x07F00000u);
    unsigned int b1 = ((q << 16) & 0x80000000u) | ((q << 12) & 0x07F00000u);
    unsigned int b2 = ((q <<  8) & 0x80000000u) | ((q <<  4) & 0x07F00000u);
    unsigned int b3 = ( q        & 0x80000000u) | ((q >>  4) & 0x07F00000u);
    acc.x = fmaf(__uint_as_float(b0), 0x1p120f, acc.x);
    acc.y = fmaf(__uint_as_float(b1), 0x1p120f, acc.y);
    acc.z = fmaf(__uint_as_float(b2), 0x1p120f, acc.z);
    acc.w = fmaf(__uint_as_float(b3), 0x1p120f, acc.w);
}

// Gather aggregation fp8 -> bf16 Ab, branchless decode, 2-way unroll.
__global__ void csr_agg_f8b_kernel(const unsigned char* __restrict__ Xq,
                                   const int* __restrict__ offsets,
                                   const int* __restrict__ srcs,
                                   unsigned short* __restrict__ Ab,
                                   int N, int D) {
    int g = (int)(((long long)blockIdx.x * blockDim.x + threadIdx.x) >> 5);
    int lane = threadIdx.x & 31;
    if (g >= N) return;
    int lo = offsets[g], hi = offsets[g + 1];
    for (int c = lane * 4; c < D; c += 128) {
        float4 acc = make_float4(0.f, 0.f, 0.f, 0.f);
        int i = lo;
        for (; i + 1 < hi; i += 2) {
            int s0 = srcs[i], s1 = srcs[i + 1];
            unsigned int q0 = *(const unsigned int*)(Xq + (size_t)s0 * D + c);
            unsigned int q1 = *(const unsigned int*)(Xq + (size_t)s1 * D + c);
            acc_fp8x4(acc, q0);
            acc_fp8x4(acc, q1);
        }
        if (i < hi) {
            int s0 = srcs[i];
            unsigned int q0 = *(const unsigned int*)(Xq + (size_t)s0 * D + c);
            acc_fp8x4(acc, q0);
        }
        ushort4 o;
        o.x = f2bf(acc.x); o.y = f2bf(acc.y);
        o.z = f2bf(acc.z); o.w = f2bf(acc.w);
        *(ushort4*)(Ab + (size_t)g * D + c) = o;
    }
}

// Gather aggregation bf16->bf16 (fallback).
__global__ void csr_agg_b2b_kernel(const unsigned short* __restrict__ Xb,
                                   const int* __restrict__ offsets,
                                   const int* __restrict__ srcs,
                                   unsigned short* __restrict__ Ab,
                                   int N, int D) {
    int g = (int)(((long long)blockIdx.x * blockDim.x + threadIdx.x) >> 5);
    int lane = threadIdx.x & 31;
    if (g >= N) return;
    int lo = offsets[g], hi = offsets[g + 1];
    for (int c = lane * 4; c < D; c += 128) {
        float4 acc = make_float4(0.f, 0.f, 0.f, 0.f);
        for (int i = lo; i < hi; i++) {
            int s = srcs[i];
            ushort4 u = *(const ushort4*)(Xb + (size_t)s * D + c);
            acc.x += bf2f(u.x); acc.y += bf2f(u.y);
            acc.z += bf2f(u.z); acc.w += bf2f(u.w);
        }
        ushort4 o;
        o.x = f2bf(acc.x); o.y = f2bf(acc.y);
        o.z = f2bf(acc.z); o.w = f2bf(acc.w);
        *(ushort4*)(Ab + (size_t)g * D + c) = o;
    }
}

// Gather aggregation from f32 X (fallback when Xb doesn't fit ws).
__global__ void csr_agg_kernel(const void* __restrict__ Xraw,
                               const int* __restrict__ offsets,
                               const int* __restrict__ srcs,
                               const int* __restrict__ flags,
                               float* __restrict__ A, int N, int D) {
    int g = (int)(((long long)blockIdx.x * blockDim.x + threadIdx.x) >> 5);
    int lane = threadIdx.x & 31;
    if (g >= N) return;
    const int isbf = flags[0];
    int lo = offsets[g], hi = offsets[g + 1];
    for (int c = lane * 4; c < D; c += 128) {
        float4 acc = make_float4(0.f, 0.f, 0.f, 0.f);
        for (int i = lo; i < hi; i++) {
            int s = srcs[i];
            float4 v = load4f(Xraw, (size_t)s * D + c, isbf);
            acc.x += v.x; acc.y += v.y; acc.z += v.z; acc.w += v.w;
        }
        *(float4*)(A + (size_t)g * D + c) = acc;
    }
}

// ---------------- MFMA GEMM (fragment-packed B) — R16 verbatim ----------------
__global__ __launch_bounds__(256) void gemm_mfma_kernel(
    const unsigned short* __restrict__ Xb,
    const unsigned short* __restrict__ Ab,
    const unsigned short* __restrict__ Wtf,
    const unsigned short* __restrict__ Wptf,
    const float* __restrict__ biasf,
    float* __restrict__ out, long long Nw) {
    const int D = 128;
    const int wave = threadIdx.x >> 6;
    const int lane = threadIdx.x & 63;
    const int lr = lane & 15;
    const int lg = lane >> 4;
    const long long rbase = ((long long)blockIdx.x * 4 + wave) * 16;
    if (rbase >= Nw) return;

    long long arow = rbase + lr;
    if (arow >= Nw) arow = Nw - 1;
    const unsigned short* xrow = Xb + arow * D;
    const unsigned short* prow = Ab + arow * D;

    f32x4 acc[8];
    #pragma unroll
    for (int i = 0; i < 8; i++) acc[i] = (f32x4){0.f, 0.f, 0.f, 0.f};

    for (int kc = 0; kc < 8; kc++) {
        const bool xpart = (kc < 4);
        const unsigned short* arow_p = xpart ? xrow : prow;
        const unsigned short* wf     = xpart ? Wtf : Wptf;
        const int kk = kc & 3;
        const int k0 = kk * 32 + 4 * lg;

        ushort4 alo = *(const ushort4*)(arow_p + k0);
        ushort4 ahi = *(const ushort4*)(arow_p + k0 + 16);
        bf16x8 a = {(short)alo.x, (short)alo.y, (short)alo.z, (short)alo.w,
                    (short)ahi.x, (short)ahi.y, (short)ahi.z, (short)ahi.w};

        #pragma unroll
        for (int ct = 0; ct < 8; ct++) {
            bf16x8 b = *(const bf16x8*)(wf +
                           ((size_t)((ct * 4 + kk) * 64 + lane)) * 8);
            acc[ct] = __builtin_amdgcn_mfma_f32_16x16x32_bf16(a, b, acc[ct],
                                                              0, 0, 0);
        }
    }

    #pragma unroll
    for (int ct = 0; ct < 8; ct++) {
        int n = ct * 16 + lr;
        float bn = biasf[n];
        #pragma unroll
        for (int r = 0; r < 4; r++) {
            long long m = rbase + 4 * lg + r;
            if (m < Nw) {
                float v = acc[ct][r] + bn;
                out[m * D + n] = v > 0.f ? v : 0.f;
            }
        }
    }
}

// ---------------- fallbacks (R9/R13-proven) ----------------
__global__ void edge_agg_kernel(const void* __restrict__ Xraw,
                                const int* __restrict__ src,
                                const int* __restrict__ dst,
                                const int* __restrict__ flags,
                                float* __restrict__ A,
                                long long E, int D, int row0, int row1) {
    long long tid = (long long)blockIdx.x * blockDim.x + threadIdx.x;
    long long e = tid >> 5;
    int lane = (int)(tid & 31);
    if (e >= E) return;
    const int is64 = flags[1];
    const int isbf = flags[0];
    long long ei = is64 ? 2 * e : e;
    int d = dst[ei];
    if (d < row0 || d >= row1) return;
    int s = src[ei];
    for (int c = lane * 4; c < D; c += 128) {
        float4 v = load4f(Xraw, (size_t)s * D + c, isbf);
        float* a = A + (size_t)(d - row0) * D + c;
        atomicAdd(a + 0, v.x);
        atomicAdd(a + 1, v.y);
        atomicAdd(a + 2, v.z);
        atomicAdd(a + 3, v.w);
    }
}

__global__ void copy_idx_kernel(const int* __restrict__ ref_a,
                                const int* __restrict__ backref,
                                const int* __restrict__ e_map,
                                const int* __restrict__ v_count,
                                const int* __restrict__ flags,
                                float* __restrict__ out,
                                long long base, long long E) {
    long long i = (long long)blockIdx.x * blockDim.x + threadIdx.x;
    const int is64 = flags[1];
    if (i < E) {
        out[base + i] = (float)ref_a[is64 ? 2 * i : i];
    } else if (i < 2 * E) {
        long long k = i - E;
        out[base + i] = (float)backref[is64 ? 2 * k : k];
    } else if (i < 3 * E) {
        out[base + i] = (float)e_map[i - 2 * E];
    } else if (i == 3 * E) {
        out[base + i] = (float)v_count[0];
    }
}

__global__ __launch_bounds__(256) void gemm_fused_kernel(
    const void* __restrict__ Xraw, const float* __restrict__ A,
    const void* __restrict__ Wraw, const void* __restrict__ Wpraw,
    const void* __restrict__ braw, const int* __restrict__ flags,
    float* __restrict__ out, long long row0, long long rend) {
    const int D = 128;
    __shared__ float sX[64][68];
    __shared__ float sW[64][68];

    const long long rbase = row0 + (long long)blockIdx.x * 64;
    const int cbase = blockIdx.y * 64;
    const int t  = threadIdx.x;
    const int tx = t & 15;
    const int ty = t >> 4;
    const int isbf = flags[0];

    float acc[4][4] = {};

    for (int kk = 0; kk < 256; kk += 64) {
        const bool first = (kk < 128);
        const void* Ws = first ? Wraw : Wpraw;
        const int kc = kk & 127;

        #pragma unroll
        for (int i = 0; i < 4; i++) {
            int r  = ty + i * 16;
            int c4 = tx * 4;
            long long grow = rbase + r;
            float4 v = make_float4(0.f, 0.f, 0.f, 0.f);
            if (grow < rend) {
                if (first)
                    v = load4f(Xraw, (size_t)grow * D + kc + c4, isbf);
                else
                    v = *(const float4*)(A + (size_t)(grow - row0) * D + kc + c4);
            }
            *(float4*)&sX[r][c4] = v;
            float4 w = load4f(Ws, (size_t)(kc + r) * D + cbase + c4, isbf);
            *(float4*)&sW[r][c4] = w;
        }
        __syncthreads();

        #pragma unroll
        for (int k4 = 0; k4 < 16; k4++) {
            float4 xv[4], wv[4];
            #pragma unroll
            for (int i = 0; i < 4; i++)
                xv[i] = *(float4*)&sX[ty * 4 + i][k4 * 4];
            #pragma unroll
            for (int i = 0; i < 4; i++)
                wv[i] = *(float4*)&sW[k4 * 4 + i][tx * 4];
            #pragma unroll
            for (int ki = 0; ki < 4; ki++) {
                #pragma unroll
                for (int r = 0; r < 4; r++) {
                    float x = (ki == 0) ? xv[r].x
                            : (ki == 1) ? xv[r].y
                            : (ki == 2) ? xv[r].z
                                        : xv[r].w;
                    acc[r][0] += x * wv[ki].x;
                    acc[r][1] += x * wv[ki].y;
                    acc[r][2] += x * wv[ki].z;
                    acc[r][3] += x * wv[ki].w;
                }
            }
        }
        __syncthreads();
    }

    const long long grow0 = rbase + ty * 4;
    const int gcol0 = cbase + tx * 4;
    float b0, b1, b2, b3;
    if (isbf) {
        const unsigned short* bb = (const unsigned short*)braw;
        b0 = bf2f(bb[gcol0 + 0]); b1 = bf2f(bb[gcol0 + 1]);
        b2 = bf2f(bb[gcol0 + 2]); b3 = bf2f(bb[gcol0 + 3]);
    } else {
        const float* bb = (const float*)braw;
        b0 = bb[gcol0 + 0]; b1 = bb[gcol0 + 1];
        b2 = bb[gcol0 + 2]; b3 = bb[gcol0 + 3];
    }
    #pragma unroll
    for (int r = 0; r < 4; r++) {
        long long grow = grow0 + r;
        if (grow >= rend) break;
        float4 v;
        v.x = acc[r][0] + b0; v.x = v.x > 0.f ? v.x : 0.f;
        v.y = acc[r][1] + b1; v.y = v.y > 0.f ? v.y : 0.f;
        v.z = acc[r][2] + b2; v.z = v.z > 0.f ? v.z : 0.f;
        v.w = acc[r][3] + b3; v.w = v.w > 0.f ? v.w : 0.f;
        *(float4*)(out + (size_t)grow * D + gcol0) = v;
    }
}

// ---------------------------------------------------------------------------
extern "C" void kernel_launch(void* const* d_in, const int* in_sizes, int n_in,
                              void* d_out, int out_size, void* d_ws, size_t ws_size,
                              hipStream_t stream) {
    const void* X       = d_in[0];
    const int*  ref_a   = (const int*)d_in[1];
    const int*  backref = (const int*)d_in[2];
    const int*  e_map   = (const int*)d_in[3];
    const int*  v_count = (const int*)d_in[4];
    const void* W       = d_in[5];
    const void* W_prop  = d_in[6];
    const void* bias    = d_in[7];
    float* out = (float*)d_out;

    int Dout = (n_in > 7 && in_sizes[7] > 0) ? in_sizes[7] : 128;
    int Din  = (in_sizes[5] > 0 && in_sizes[5] % Dout == 0)
                   ? in_sizes[5] / Dout : Dout;
    long long N = in_sizes[0] / Din;
    long long E = in_sizes[1];
    long long base = (long long)out_size - 3 * E - 1;
    if (base < 0) base = N * Dout;

    // ---- workspace layout ----
    auto align256 = [](size_t x) { return (x + 255) & ~(size_t)255; };
    size_t o_flags = 0;
    size_t o_off   = align256(o_flags + 256);
    size_t o_cur   = align256(o_off + (size_t)(N + 1) * 4);
    size_t o_bsum  = align256(o_cur + (size_t)N * 4);
    size_t o_srcs  = align256(o_bsum + 1024 * 4);
    size_t o_A     = align256(o_srcs + (size_t)E * 4);
    size_t o_Xb    = align256(o_A + (size_t)N * Din * 4);
    size_t o_Wt    = align256(o_Xb + (size_t)N * Din * 2);
    size_t o_Wpt   = align256(o_Wt + (size_t)Din * Dout * 2);
    size_t o_bf    = align256(o_Wpt + (size_t)Din * Dout * 2);
    size_t o_Xq    = align256(o_bf + (size_t)Dout * 4);
    size_t need_csr  = o_Xb;
    size_t need_mfma = o_Xq;
    size_t need_fp8  = o_Xq + (size_t)N * Din;
    const bool use_csr  = (ws_size >= need_csr);
    const bool use_mfma = (ws_size >= need_mfma) && (Din == 128) && (Dout == 128);
    const bool use_fp8  = (ws_size >= need_fp8) && use_mfma;

    char* wsb = (char*)d_ws;
    int*            flags   = (int*)(wsb + o_flags);
    int*            offsets = (int*)(wsb + o_off);
    int*            cursor  = (int*)(wsb + o_cur);
    int*            bsum    = (int*)(wsb + o_bsum);
    int*            srcs    = (int*)(wsb + o_srcs);
    float*          A       = use_csr ? (float*)(wsb + o_A) : (float*)(wsb + 256);
    unsigned short* Ab      = (unsigned short*)(wsb + o_A);
    unsigned short* Xb      = (unsigned short*)(wsb + o_Xb);
    unsigned short* Wtf     = (unsigned short*)(wsb + o_Wt);
    unsigned short* Wptf    = (unsigned short*)(wsb + o_Wpt);
    float*          biasf   = (float*)(wsb + o_bf);
    unsigned char*  Xq      = (unsigned char*)(wsb + o_Xq);

    detect_kernel<<<1, 256, 0, stream>>>((const unsigned int*)X,
                                         (const unsigned int*)backref, flags);

    long long Nw = N;
    long long cap = base / Dout;
    if (cap < Nw) Nw = cap;
    if (N * Dout < base)
        fill_zero_f32<<<2048, 1024, 0, stream>>>(out, N * Dout, base);

    if (use_csr) {
        // ---- counts=0; fused idx copy + histogram ----
        zero_i32<<<256, 256, 0, stream>>>(cursor, N);
        {
            long long total = 3 * E + 1;
            int blocks = (int)((total + 255) / 256);
            copy_idx_hist_kernel<<<blocks, 256, 0, stream>>>(
                ref_a, backref, e_map, v_count, flags, out, cursor, base, E);
        }
        // ---- 3-phase scan -> offsets, cursor ----
        int nb = (int)((N + SCAN_BE - 1) / SCAN_BE);
        if (nb <= 1024) {
            block_reduce_kernel<<<nb, 256, 0, stream>>>(cursor, bsum, (int)N);
            scan_bsum_kernel<<<1, 1024, 0, stream>>>(bsum, nb, offsets, (int)N);
            block_scan_kernel<<<nb, 256, 0, stream>>>(cursor, bsum, offsets,
                                                      cursor, (int)N);
        } else {
            scan_kernel<<<1, 1024, 0, stream>>>(cursor, offsets, cursor, (int)N);
        }
        // ---- scatter: XCD-range partitioned (R19-proven) ----
        {
            const int nstripes = 256;
            scatter_xcd_kernel<<<8 * nstripes, 256, 0, stream>>>(
                ref_a, backref, flags, cursor, srcs, E, (int)N, nstripes);
        }

        if (use_mfma) {
            {
                long long n4 = (N * (long long)Din) / 4;
                int cblocks = (int)((n4 + 1023) / 1024);
                if (cblocks > 2048) cblocks = 2048;
                xconv_dual_kernel<<<cblocks, 1024, 0, stream>>>(
                    X, flags, Xb, Xq, use_fp8 ? 1 : 0, n4);
            }
            wtrans_frag_kernel<<<8, 256, 0, stream>>>(W, W_prop, bias, flags,
                                                      Wtf, Wptf, biasf, Din);
            {
                long long threads = N * 32;
                int blocks = (int)((threads + 255) / 256);
                if (use_fp8)
                    csr_agg_f8b_kernel<<<blocks, 256, 0, stream>>>(
                        Xq, offsets, srcs, Ab, (int)N, Din);
                else
                    csr_agg_b2b_kernel<<<blocks, 256, 0, stream>>>(
                        Xb, offsets, srcs, Ab, (int)N, Din);
            }
            {
                int blocks = (int)((Nw + 63) / 64);
                gemm_mfma_kernel<<<blocks, 256, 0, stream>>>(Xb, Ab, Wtf, Wptf,
                                                             biasf, out, Nw);
            }
        } else {
            {
                long long threads = N * 32;
                int blocks = (int)((threads + 255) / 256);
                csr_agg_kernel<<<blocks, 256, 0, stream>>>(X, offsets, srcs,
                                                           flags, A, (int)N, Din);
            }
            dim3 grid((unsigned)((Nw + 63) / 64), 2);
            gemm_fused_kernel<<<grid, 256, 0, stream>>>(X, A, W, W_prop, bias,
                                                        flags, out, 0, Nw);
        }
    } else {
        // ---- fallback: chunked atomic path (R9-proven) ----
        {
            long long total = 3 * E + 1;
            int blocks = (int)((total + 255) / 256);
            copy_idx_kernel<<<blocks, 256, 0, stream>>>(ref_a, backref, e_map,
                                                        v_count, flags, out,
                                                        base, E);
        }
        size_t avail = (ws_size > 256) ? ws_size - 256 : 0;
        size_t rows_cap = avail / ((size_t)Din * sizeof(float));
        long long rows_per;
        if (rows_cap >= (size_t)Nw) rows_per = Nw > 0 ? Nw : 1;
        else {
            rows_per = (long long)(rows_cap & ~(size_t)63);
            if (rows_per <= 0) rows_per = 64;
        }
        for (long long row0 = 0; row0 < Nw; row0 += rows_per) {
            long long rows = (Nw - row0 < rows_per) ? (Nw - row0) : rows_per;
            long long rend = row0 + rows;
            {   long long n4 = (rows * (long long)Din) / 4;
                int blocks = (int)((n4 + 1023) / 1024);
                if (blocks > 2048) blocks = 2048;
                if (blocks > 0)
                    zero_kernel<<<blocks, 1024, 0, stream>>>((float4*)A, n4);
            }
            {   long long threads = E * 32;
                int blocks = (int)((threads + 255) / 256);
                edge_agg_kernel<<<blocks, 256, 0, stream>>>(X, ref_a, backref,
                                                            flags, A, E, Din,
                                                            (int)row0, (int)rend);
            }
            {   dim3 grid((unsigned)((rows + 63) / 64), 2);
                gemm_fused_kernel<<<grid, 256, 0, stream>>>(X, A, W, W_prop,
                                                            bias, flags, out,
                                                            row0, rend);
            }
        }
    }
}